// Round 1
// baseline (85.314 us; speedup 1.0000x reference)
//
#include <hip/hip_runtime.h>

#define N_ATOMS 1536
#define FEAT    32
#define N_GAUSS 16
#define MAXNBR  512   // expected ~30 neighbors; Poisson tail makes 512 unreachable

__global__ __launch_bounds__(64) void gnn_energy_kernel(
    const float* __restrict__ xyz, const int* __restrict__ z,
    const float* __restrict__ emb, const float* __restrict__ W1,
    const float* __restrict__ b1,  const float* __restrict__ W2,
    const float* __restrict__ b2,  const float* __restrict__ W3,
    const float* __restrict__ b3,  float* __restrict__ out)
{
    const int i    = blockIdx.x;
    const int lane = threadIdx.x;   // one wave of 64

    __shared__ float sW1[N_GAUSS * FEAT];
    __shared__ float sW2[FEAT * FEAT];
    __shared__ int   s_nbr[MAXNBR];
    __shared__ float s_dist[MAXNBR];
    __shared__ int   s_cnt;

    for (int t = lane; t < N_GAUSS * FEAT; t += 64) sW1[t] = W1[t];
    for (int t = lane; t < FEAT * FEAT;    t += 64) sW2[t] = W2[t];
    if (lane == 0) s_cnt = 0;
    __syncthreads();

    const float xi = xyz[3*i+0], yi = xyz[3*i+1], zi = xyz[3*i+2];

    // ---- Phase A: cheap N-scan, compact hits into LDS queue ----
    for (int j = lane; j < N_ATOMS; j += 64) {
        float dx = xyz[3*j+0] - xi;   // disp[i,j] = xyz[j] - xyz[i]
        float dy = xyz[3*j+1] - yi;
        float dz = xyz[3*j+2] - zi;
        // minimum-image wrap, matching reference: shift = (d < -15) - (d >= 15)
        dx += (dx < -15.0f ? 30.0f : 0.0f) - (dx >= 15.0f ? 30.0f : 0.0f);
        dy += (dy < -15.0f ? 30.0f : 0.0f) - (dy >= 15.0f ? 30.0f : 0.0f);
        dz += (dz < -15.0f ? 30.0f : 0.0f) - (dz >= 15.0f ? 30.0f : 0.0f);
        float d2 = dx*dx + dy*dy + dz*dz;
        if (d2 < 25.0f && d2 > 0.0f) {
            int slot = atomicAdd(&s_cnt, 1);
            if (slot < MAXNBR) { s_nbr[slot] = j; s_dist[slot] = sqrtf(d2); }
        }
    }
    __syncthreads();
    const int cnt = min(s_cnt, MAXNBR);

    // ---- Phase B: dense pair work on compacted list ----
    float agg[FEAT];
    #pragma unroll
    for (int f = 0; f < FEAT; ++f) agg[f] = 0.0f;

    for (int p = lane; p < cnt; p += 64) {
        const int   j = s_nbr[p];
        const float d = s_dist[p];
        float rbf[N_GAUSS];
        #pragma unroll
        for (int g = 0; g < N_GAUSS; ++g) {
            float t = d - (float)g * (5.0f / 15.0f);   // mu_g = linspace(0,5,16)
            rbf[g] = __expf(-10.0f * t * t);
        }
        const float* hj = emb + z[j] * FEAT;
        #pragma unroll
        for (int f = 0; f < FEAT; ++f) {
            float s = b1[f];
            #pragma unroll
            for (int g = 0; g < N_GAUSS; ++g) s += rbf[g] * sW1[g * FEAT + f];
            agg[f] += tanhf(s) * hj[f];
        }
    }

    // ---- butterfly all-reduce of agg across the 64-lane wave ----
    #pragma unroll
    for (int f = 0; f < FEAT; ++f) {
        #pragma unroll
        for (int off = 32; off > 0; off >>= 1)
            agg[f] += __shfl_xor(agg[f], off, 64);
    }

    // ---- per-atom MLP: u = silu((h+agg)@W2+b2); e = u@W3 + b3 ----
    const float* hi = emb + z[i] * FEAT;
    float e = 0.0f;
    if (lane < FEAT) {
        float s = b2[lane];
        #pragma unroll
        for (int k = 0; k < FEAT; ++k)
            s += (hi[k] + agg[k]) * sW2[k * FEAT + lane];
        float u = s / (1.0f + __expf(-s));   // silu
        e = u * W3[lane];
    }
    #pragma unroll
    for (int off = 32; off > 0; off >>= 1)
        e += __shfl_xor(e, off, 64);

    if (lane == 0) atomicAdd(out, e + b3[0]);
}

extern "C" void kernel_launch(void* const* d_in, const int* in_sizes, int n_in,
                              void* d_out, int out_size, void* d_ws, size_t ws_size,
                              hipStream_t stream) {
    const float* xyz = (const float*)d_in[0];
    const int*   z   = (const int*)  d_in[1];
    const float* emb = (const float*)d_in[2];
    const float* W1  = (const float*)d_in[3];
    const float* b1  = (const float*)d_in[4];
    const float* W2  = (const float*)d_in[5];
    const float* b2  = (const float*)d_in[6];
    const float* W3  = (const float*)d_in[7];
    const float* b3  = (const float*)d_in[8];
    float* out = (float*)d_out;

    hipMemsetAsync(out, 0, sizeof(float), stream);
    gnn_energy_kernel<<<N_ATOMS, 64, 0, stream>>>(xyz, z, emb, W1, b1, W2, b2, W3, b3, out);
}

// Round 2
// 43.472 us; speedup vs baseline: 1.9625x; 1.9625x over previous
//
#include <hip/hip_runtime.h>

#define N_ATOMS  1536
#define FEAT     32
#define N_GAUSS  16
#define N_TYPES  10
#define MAXNBR   256     // expected ~30 neighbors/atom; 256 is +40σ
#define NTHREADS 256

__global__ __launch_bounds__(NTHREADS, 4) void gnn_energy_kernel(
    const float* __restrict__ xyz, const int* __restrict__ z,
    const float* __restrict__ emb, const float* __restrict__ W1,
    const float* __restrict__ b1,  const float* __restrict__ W2,
    const float* __restrict__ b2,  const float* __restrict__ W3,
    const float* __restrict__ b3,  float* __restrict__ out)
{
    const int i    = blockIdx.x;
    const int tid  = threadIdx.x;
    const int lane = tid & 63;
    const int wid  = tid >> 6;

    __shared__ float sW1[N_GAUSS * FEAT];      // [g][f]
    __shared__ float sW2[FEAT * FEAT];         // [k][f]
    __shared__ float sB1[FEAT];
    __shared__ float sEmbT[FEAT * N_TYPES];    // transposed: [f][type] -> bank-spread gather
    __shared__ int   s_nbr[MAXNBR];
    __shared__ float s_dist[MAXNBR];
    __shared__ float s_red[4 * FEAT];          // per-wave partial agg
    __shared__ float s_x[FEAT];                // MLP input h+agg
    __shared__ int   s_cnt;

    // ---- cooperative staging (6-8 loads/thread) ----
    for (int t = tid; t < N_GAUSS * FEAT; t += NTHREADS) sW1[t] = W1[t];
    for (int t = tid; t < FEAT * FEAT;    t += NTHREADS) sW2[t] = W2[t];
    for (int t = tid; t < FEAT * N_TYPES; t += NTHREADS) {
        int f = t / N_TYPES, ty = t % N_TYPES;
        sEmbT[t] = emb[ty * FEAT + f];
    }
    if (tid < FEAT) sB1[tid] = b1[tid];
    if (tid < 4 * FEAT) s_red[tid] = 0.0f;
    if (tid == 0) s_cnt = 0;
    __syncthreads();

    const float xi = xyz[3*i+0], yi = xyz[3*i+1], zi = xyz[3*i+2];

    // ---- Phase A: N-scan across 256 threads (6 iterations), compact hits ----
    for (int j = tid; j < N_ATOMS; j += NTHREADS) {
        float dx = xyz[3*j+0] - xi;
        float dy = xyz[3*j+1] - yi;
        float dz = xyz[3*j+2] - zi;
        dx += (dx < -15.0f ? 30.0f : 0.0f) - (dx >= 15.0f ? 30.0f : 0.0f);
        dy += (dy < -15.0f ? 30.0f : 0.0f) - (dy >= 15.0f ? 30.0f : 0.0f);
        dz += (dz < -15.0f ? 30.0f : 0.0f) - (dz >= 15.0f ? 30.0f : 0.0f);
        float d2 = dx*dx + dy*dy + dz*dz;
        if (d2 < 25.0f && d2 > 0.0f) {
            int slot = atomicAdd(&s_cnt, 1);
            if (slot < MAXNBR) { s_nbr[slot] = j; s_dist[slot] = sqrtf(d2); }
        }
    }
    __syncthreads();
    const int cnt = min(s_cnt, MAXNBR);

    // ---- Phase B: dense pair work (one pass: cnt ~30 << 256) ----
    float agg[FEAT];
    #pragma unroll
    for (int f = 0; f < FEAT; ++f) agg[f] = 0.0f;

    for (int p = tid; p < cnt; p += NTHREADS) {
        const int   j  = s_nbr[p];
        const float d  = s_dist[p];
        const int   zj = z[j];
        float rbf[N_GAUSS];
        #pragma unroll
        for (int g = 0; g < N_GAUSS; ++g) {
            float t = d - (float)g * (5.0f / 15.0f);
            rbf[g] = __expf(-10.0f * t * t);
        }
        #pragma unroll
        for (int f = 0; f < FEAT; ++f) {
            float s = sB1[f];
            #pragma unroll
            for (int g = 0; g < N_GAUSS; ++g) s = fmaf(rbf[g], sW1[g * FEAT + f], s);
            // fast tanh via expf, overflow-safe
            float t2 = __expf(-2.0f * fabsf(s));
            float th = copysignf((1.0f - t2) / (1.0f + t2), s);
            agg[f] += th * sEmbT[f * N_TYPES + zj];
        }
    }

    // ---- reduce agg: butterfly in wave 0 (others are zero unless cnt>64) ----
    if (wid == 0 || cnt > 64) {
        #pragma unroll
        for (int f = 0; f < FEAT; ++f) {
            #pragma unroll
            for (int off = 32; off > 0; off >>= 1)
                agg[f] += __shfl_xor(agg[f], off, 64);
        }
        if (lane == 0) {
            #pragma unroll
            for (int f = 0; f < FEAT; ++f) s_red[wid * FEAT + f] = agg[f];
        }
    }
    __syncthreads();
    if (tid < FEAT) {
        float a = s_red[tid] + s_red[FEAT + tid] + s_red[2*FEAT + tid] + s_red[3*FEAT + tid];
        s_x[tid] = a + emb[z[i] * FEAT + tid];   // h + agg
    }
    __syncthreads();

    // ---- MLP on wave 0 lanes 0..31: u = silu(x@W2+b2); e = u@W3 ----
    if (tid < FEAT) {
        float s = b2[tid];
        #pragma unroll
        for (int k = 0; k < FEAT; ++k) s = fmaf(s_x[k], sW2[k * FEAT + tid], s);
        float u = s / (1.0f + __expf(-s));       // silu
        float e = u * W3[tid];
        #pragma unroll
        for (int off = 16; off > 0; off >>= 1)
            e += __shfl_xor(e, off, 64);
        if (tid == 0) atomicAdd(out, e + b3[0]);
    }
}

extern "C" void kernel_launch(void* const* d_in, const int* in_sizes, int n_in,
                              void* d_out, int out_size, void* d_ws, size_t ws_size,
                              hipStream_t stream) {
    const float* xyz = (const float*)d_in[0];
    const int*   z   = (const int*)  d_in[1];
    const float* emb = (const float*)d_in[2];
    const float* W1  = (const float*)d_in[3];
    const float* b1  = (const float*)d_in[4];
    const float* W2  = (const float*)d_in[5];
    const float* b2  = (const float*)d_in[6];
    const float* W3  = (const float*)d_in[7];
    const float* b3  = (const float*)d_in[8];
    float* out = (float*)d_out;

    hipMemsetAsync(out, 0, sizeof(float), stream);
    gnn_energy_kernel<<<N_ATOMS, NTHREADS, 0, stream>>>(xyz, z, emb, W1, b1, W2, b2, W3, b3, out);
}

// Round 3
// 26.147 us; speedup vs baseline: 3.2628x; 1.6626x over previous
//
#include <hip/hip_runtime.h>

#define N_ATOMS  1536
#define FEAT     32
#define N_GAUSS  16
#define N_TYPES  10
#define MAXNBR   256     // expected ~30 neighbors/atom; +40 sigma headroom
#define NTHREADS 256
#define NSTAGE   1888    // 512 (W1) + 1024 (W2) + 320 (embT) + 32 (b1)

__global__ __launch_bounds__(NTHREADS, 4) void gnn_atom_kernel(
    const float* __restrict__ xyz, const int* __restrict__ z,
    const float* __restrict__ emb, const float* __restrict__ W1,
    const float* __restrict__ b1,  const float* __restrict__ W2,
    const float* __restrict__ b2,  const float* __restrict__ W3,
    float* __restrict__ e_atom)
{
    const int i    = blockIdx.x;
    const int tid  = threadIdx.x;
    const int lane = tid & 63;
    const int wid  = tid >> 6;

    __shared__ float sStage[NSTAGE];
    float* sW1   = sStage;           // [g][f]
    float* sW2   = sStage + 512;     // [k][f]
    float* sEmbT = sStage + 1536;    // [f][type]
    float* sB1   = sStage + 1856;
    __shared__ int   s_nbr[MAXNBR];
    __shared__ float s_dist[MAXNBR];
    __shared__ float s_red[4 * FEAT];
    __shared__ float s_x[FEAT];
    __shared__ int   s_cnt;

    // ---- issue weight-staging loads into REGISTERS now; LDS-write after scan
    //      (HBM/L2 latency hides under Phase A) ----
    float rs[8];
    #pragma unroll
    for (int k = 0; k < 8; ++k) {
        int v = tid + k * NTHREADS;
        float val = 0.0f;
        if (v < 512)        val = W1[v];
        else if (v < 1536)  val = W2[v - 512];
        else if (v < 1856) { int u = v - 1536; val = emb[(u % N_TYPES) * FEAT + (u / N_TYPES)]; }
        else if (v < NSTAGE) val = b1[v - 1856];
        rs[k] = val;
    }

    if (tid == 0) s_cnt = 0;
    if (tid < 4 * FEAT) s_red[tid] = 0.0f;
    __syncthreads();   // s_cnt visible before Phase A atomics

    const float xi = xyz[3*i+0], yi = xyz[3*i+1], zi = xyz[3*i+2];

    // ---- Phase A: N-scan across 256 threads, compact hits into LDS queue ----
    for (int j = tid; j < N_ATOMS; j += NTHREADS) {
        float dx = xyz[3*j+0] - xi;
        float dy = xyz[3*j+1] - yi;
        float dz = xyz[3*j+2] - zi;
        dx += (dx < -15.0f ? 30.0f : 0.0f) - (dx >= 15.0f ? 30.0f : 0.0f);
        dy += (dy < -15.0f ? 30.0f : 0.0f) - (dy >= 15.0f ? 30.0f : 0.0f);
        dz += (dz < -15.0f ? 30.0f : 0.0f) - (dz >= 15.0f ? 30.0f : 0.0f);
        float d2 = dx*dx + dy*dy + dz*dz;
        if (d2 < 25.0f && d2 > 0.0f) {
            int slot = atomicAdd(&s_cnt, 1);
            if (slot < MAXNBR) { s_nbr[slot] = j; s_dist[slot] = sqrtf(d2); }
        }
    }

    // ---- now commit staged weights to LDS (loads long since landed) ----
    #pragma unroll
    for (int k = 0; k < 8; ++k) {
        int v = tid + k * NTHREADS;
        if (v < NSTAGE) sStage[v] = rs[k];
    }
    __syncthreads();
    const int cnt = min(s_cnt, MAXNBR);

    // ---- Phase B: dense pair work (cnt ~30 << 256 -> one pass) ----
    float agg[FEAT];
    #pragma unroll
    for (int f = 0; f < FEAT; ++f) agg[f] = 0.0f;

    for (int p = tid; p < cnt; p += NTHREADS) {
        const int   j  = s_nbr[p];
        const float d  = s_dist[p];
        const int   zj = z[j];
        float rbf[N_GAUSS];
        #pragma unroll
        for (int g = 0; g < N_GAUSS; ++g) {
            float t = d - (float)g * (5.0f / 15.0f);
            rbf[g] = __expf(-10.0f * t * t);
        }
        #pragma unroll
        for (int f = 0; f < FEAT; ++f) {
            float s = sB1[f];
            #pragma unroll
            for (int g = 0; g < N_GAUSS; ++g) s = fmaf(rbf[g], sW1[g * FEAT + f], s);
            float t2 = __expf(-2.0f * fabsf(s));
            float th = copysignf((1.0f - t2) / (1.0f + t2), s);
            agg[f] += th * sEmbT[f * N_TYPES + zj];
        }
    }

    // ---- reduce agg: butterfly in wave 0 (others hold zeros unless cnt>64) ----
    if (wid == 0 || cnt > 64) {
        #pragma unroll
        for (int f = 0; f < FEAT; ++f) {
            #pragma unroll
            for (int off = 32; off > 0; off >>= 1)
                agg[f] += __shfl_xor(agg[f], off, 64);
        }
        if (lane == 0) {
            #pragma unroll
            for (int f = 0; f < FEAT; ++f) s_red[wid * FEAT + f] = agg[f];
        }
    }
    __syncthreads();
    if (tid < FEAT) {
        float a = s_red[tid] + s_red[FEAT + tid] + s_red[2*FEAT + tid] + s_red[3*FEAT + tid];
        s_x[tid] = a + emb[z[i] * FEAT + tid];   // h + agg
    }
    __syncthreads();

    // ---- MLP on wave 0 lanes 0..31; plain per-atom store (NO global atomic) ----
    if (tid < FEAT) {
        float s = b2[tid];
        #pragma unroll
        for (int k = 0; k < FEAT; ++k) s = fmaf(s_x[k], sW2[k * FEAT + tid], s);
        float u = s / (1.0f + __expf(-s));       // silu
        float e = u * W3[tid];
        #pragma unroll
        for (int off = 16; off > 0; off >>= 1)
            e += __shfl_xor(e, off, 64);
        if (tid == 0) e_atom[i] = e;
    }
}

__global__ __launch_bounds__(NTHREADS) void gnn_reduce_kernel(
    const float* __restrict__ e_atom, const float* __restrict__ b3,
    float* __restrict__ out)
{
    const int tid = threadIdx.x;
    float s = 0.0f;
    for (int t = tid; t < N_ATOMS; t += NTHREADS) s += e_atom[t];
    #pragma unroll
    for (int off = 32; off > 0; off >>= 1)
        s += __shfl_xor(s, off, 64);
    __shared__ float r[4];
    if ((tid & 63) == 0) r[tid >> 6] = s;
    __syncthreads();
    if (tid == 0)
        out[0] = r[0] + r[1] + r[2] + r[3] + (float)N_ATOMS * b3[0];
}

extern "C" void kernel_launch(void* const* d_in, const int* in_sizes, int n_in,
                              void* d_out, int out_size, void* d_ws, size_t ws_size,
                              hipStream_t stream) {
    const float* xyz = (const float*)d_in[0];
    const int*   z   = (const int*)  d_in[1];
    const float* emb = (const float*)d_in[2];
    const float* W1  = (const float*)d_in[3];
    const float* b1  = (const float*)d_in[4];
    const float* W2  = (const float*)d_in[5];
    const float* b2  = (const float*)d_in[6];
    const float* W3  = (const float*)d_in[7];
    const float* b3  = (const float*)d_in[8];
    float* out    = (float*)d_out;
    float* e_atom = (float*)d_ws;     // 1536 floats of scratch

    gnn_atom_kernel<<<N_ATOMS, NTHREADS, 0, stream>>>(xyz, z, emb, W1, b1, W2, b2, W3, e_atom);
    gnn_reduce_kernel<<<1, NTHREADS, 0, stream>>>(e_atom, b3, out);
}